// Round 7
// baseline (87.266 us; speedup 1.0000x reference)
//
#include <hip/hip_runtime.h>
#include <float.h>

#define H_IN 224
#define W_IN 224
#define H_T  240
#define W_T  240
#define S1   17
#define S2   17
#define NS   (S1*S2)          // 289
#define NB   8
#define NPIX (H_IN*W_IN)      // 50176
#define TPIX (H_T*W_T)        // 57600
#define ROWG 4
#define ROWS_PER_BLOCK (H_IN/ROWG)        // 56
#define ROWS_PER_WAVE  (ROWS_PER_BLOCK/4) // 14
#define PB   (NPIX/256)       // 196 copy-blocks per sample

// ws float layout:
//   part : [B][S1][ROWG][S2]  -> 9248 floats @ 0
//   fpart: [B][ROWG]          -> 32 floats @ 9248
#define WS_PART  0
#define WS_FPART 9248

// ---------------- kernel 1: corr partials + fused f(l) partials ----------------
__global__ __launch_bounds__(256) void corr_f_kernel(const float* __restrict__ logits,
                                                     const float* __restrict__ targ,
                                                     float* __restrict__ ws) {
    int bid  = blockIdx.x;              // b*S1*ROWG + i*ROWG + rg
    int rg   = bid % ROWG;
    int i    = (bid / ROWG) % S1;
    int b    = bid / (ROWG * S1);
    int tid  = threadIdx.x;
    int lane = tid & 63;
    int w    = tid >> 6;
    bool active = lane < (W_IN / 4);    // 56 active lanes

    float acc[S2];
#pragma unroll
    for (int j = 0; j < S2; ++j) acc[j] = 0.f;
    float fs = 0.f;

    const float* Lb = logits + b * NPIX;
    const float* Tb = targ   + b * TPIX;
    const int y0 = rg * ROWS_PER_BLOCK + w * ROWS_PER_WAVE;
    const bool do_f = (i == 0);

    for (int r = 0; r < ROWS_PER_WAVE; ++r) {
        int y = y0 + r;
        if (active) {
            const float4 l4 = *(const float4*)(Lb + y * W_IN + lane * 4);
            const float* Tr = Tb + (y + i) * W_T + lane * 4;
            float4 t0 = *(const float4*)(Tr);
            float4 t1 = *(const float4*)(Tr + 4);
            float4 t2 = *(const float4*)(Tr + 8);
            float4 t3 = *(const float4*)(Tr + 12);
            float4 t4 = *(const float4*)(Tr + 16);
            float t[20] = {t0.x,t0.y,t0.z,t0.w, t1.x,t1.y,t1.z,t1.w,
                           t2.x,t2.y,t2.z,t2.w, t3.x,t3.y,t3.z,t3.w,
                           t4.x,t4.y,t4.z,t4.w};
            float l[4] = {l4.x, l4.y, l4.z, l4.w};
#pragma unroll
            for (int j = 0; j < S2; ++j) {
                float s = acc[j];
                s = fmaf(l[0], t[j],     s);
                s = fmaf(l[1], t[j + 1], s);
                s = fmaf(l[2], t[j + 2], s);
                s = fmaf(l[3], t[j + 3], s);
                acc[j] = s;
            }
            if (do_f) {
#pragma unroll
                for (int u = 0; u < 4; ++u) {
                    float v = l[u];
                    fs += fmaxf(v, 0.f) + __logf(1.f + __expf(-fabsf(v)));
                }
            }
        }
    }

#pragma unroll
    for (int j = 0; j < S2; ++j) {
        float v = acc[j];
#pragma unroll
        for (int off = 32; off > 0; off >>= 1)
            v += __shfl_xor(v, off, 64);
        acc[j] = v;
    }

    __shared__ float red[4][S2];
    __shared__ float redf[4];
    if (lane == 0) {
#pragma unroll
        for (int j = 0; j < S2; ++j) red[w][j] = acc[j];
    }
    if (do_f) {
#pragma unroll
        for (int off = 32; off > 0; off >>= 1)
            fs += __shfl_xor(fs, off, 64);
        if (lane == 0) redf[w] = fs;
    }
    __syncthreads();
    if (tid < S2) {
        float v = red[0][tid] + red[1][tid] + red[2][tid] + red[3][tid];
        ws[WS_PART + ((b * S1 + i) * ROWG + rg) * S2 + tid] = v;
    }
    if (do_f && tid == 0)
        ws[WS_FPART + b * ROWG + rg] = redf[0] + redf[1] + redf[2] + redf[3];
}

// ---------------- kernel 2: argmax + copy + loss (round-4 proven) ----------------
__device__ __forceinline__ void argmax_for(const float* __restrict__ part, int bb,
                                           int tid, int lane, int w,
                                           float* s_v, int* s_i,
                                           float& o_v, int& o_i) {
    float bv = -FLT_MAX;
    int   bs = NS;
    for (int s = tid; s < NS; s += 256) {
        const float* pp = part + ((bb * S1 + s / S2) * ROWG) * S2 + (s % S2);
        float v = pp[0] + pp[S2] + pp[2 * S2] + pp[3 * S2];
        if (v > bv) { bv = v; bs = s; } // s ascending -> earliest tie kept
    }
#pragma unroll
    for (int off = 32; off > 0; off >>= 1) {
        float ov = __shfl_down(bv, off, 64);
        int   oi = __shfl_down(bs, off, 64);
        if (ov > bv || (ov == bv && oi < bs)) { bv = ov; bs = oi; }
    }
    if (lane == 0) { s_v[w] = bv; s_i[w] = bs; }
    __syncthreads();
    if (tid == 0) {
        float fv = s_v[0]; int fi = s_i[0];
#pragma unroll
        for (int k = 1; k < 4; ++k) {
            if (s_v[k] > fv || (s_v[k] == fv && s_i[k] < fi)) { fv = s_v[k]; fi = s_i[k]; }
        }
        s_v[4] = fv; s_i[4] = fi;
    }
    __syncthreads();
    o_v = s_v[4];
    o_i = s_i[4];
}

__device__ __forceinline__ void argmax_all8(const float* __restrict__ part,
                                            int lane, int w,
                                            float* s_v8, int* s_i8) {
#pragma unroll
    for (int pass = 0; pass < 2; ++pass) {
        int bb = w + pass * 4;
        float bv2 = -FLT_MAX;
        int   bs2 = NS;
        for (int s = lane; s < NS; s += 64) {
            const float* pp = part + ((bb * S1 + s / S2) * ROWG) * S2 + (s % S2);
            float v = pp[0] + pp[S2] + pp[2 * S2] + pp[3 * S2];
            if (v > bv2) { bv2 = v; bs2 = s; }
        }
#pragma unroll
        for (int off = 32; off > 0; off >>= 1) {
            float ov = __shfl_down(bv2, off, 64);
            int   oi = __shfl_down(bs2, off, 64);
            if (ov > bv2 || (ov == bv2 && oi < bs2)) { bv2 = ov; bs2 = oi; }
        }
        if (lane == 0) { s_v8[bb] = bv2; s_i8[bb] = bs2; }
    }
    __syncthreads();
}

__global__ __launch_bounds__(256) void finish_kernel(const float* __restrict__ targ,
                                                     const float* __restrict__ ws,
                                                     float* __restrict__ out) {
    int blk = blockIdx.x;               // b*PB + p
    int p   = blk % PB;
    int b   = blk / PB;
    int tid = threadIdx.x;
    int lane = tid & 63;
    int w    = tid >> 6;

    const float* part  = ws + WS_PART;
    const float* fpart = ws + WS_FPART;

    __shared__ float s_v[5];
    __shared__ int   s_i[5];
    __shared__ float s_v8[NB];
    __shared__ int   s_i8[NB];

    int best;
    if (blk == 0) {
        argmax_all8(part, lane, w, s_v8, s_i8);
        if (tid == 0) {
            float total = 0.f;
#pragma unroll
            for (int bb = 0; bb < NB; ++bb) {
                float F = fpart[bb * ROWG] + fpart[bb * ROWG + 1] +
                          fpart[bb * ROWG + 2] + fpart[bb * ROWG + 3];
                total += (F - s_v8[bb]) * (1.0f / (float)NPIX);
            }
            out[0] = total;
        }
        best = s_i8[0];
    } else {
        float bv;
        argmax_for(part, b, tid, lane, w, s_v, s_i, bv, best);
    }

    int pix = p * 256 + tid;            // < 50176 exactly
    int y = pix / W_IN;
    int x = pix - y * W_IN;
    int i = best / S2;
    int j = best - i * S2;
    out[1 + b * NPIX + pix] = targ[b * TPIX + (y + i) * W_T + (x + j)];
}

extern "C" void kernel_launch(void* const* d_in, const int* in_sizes, int n_in,
                              void* d_out, int out_size, void* d_ws, size_t ws_size,
                              hipStream_t stream) {
    const float* logits = (const float*)d_in[0];   // [8,1,224,224]
    const float* targ   = (const float*)d_in[1];   // [8,1,240,240]
    float* out = (float*)d_out;                    // [1 + 8*224*224]
    float* ws  = (float*)d_ws;

    // DECOMPOSITION EXPERIMENT: corr x5 (idempotent, identical writes) + finish x1.
    // dur = 5C + F + 6L = 25.9 + 4*(C+L). Result pins corr-vs-finish attribution.
    corr_f_kernel<<<NB * S1 * ROWG, 256, 0, stream>>>(logits, targ, ws);
    corr_f_kernel<<<NB * S1 * ROWG, 256, 0, stream>>>(logits, targ, ws);
    corr_f_kernel<<<NB * S1 * ROWG, 256, 0, stream>>>(logits, targ, ws);
    corr_f_kernel<<<NB * S1 * ROWG, 256, 0, stream>>>(logits, targ, ws);
    corr_f_kernel<<<NB * S1 * ROWG, 256, 0, stream>>>(logits, targ, ws);
    finish_kernel<<<NB * PB, 256, 0, stream>>>(targ, ws, out);
}

// Round 8
// 26.212 us; speedup vs baseline: 3.3292x; 3.3292x over previous
//
#include <hip/hip_runtime.h>
#include <float.h>

#define H_IN 224
#define W_IN 224
#define H_T  240
#define W_T  240
#define S1   17
#define S2   17
#define NS   (S1*S2)          // 289
#define NB   8
#define NPIX (H_IN*W_IN)      // 50176
#define TPIX (H_T*W_T)        // 57600
#define RG   8                // row-groups per sample-shift (was 4)
#define ROWS_PER_BLOCK (H_IN/RG)          // 28
#define ROWS_PER_WAVE  (ROWS_PER_BLOCK/4) // 7
#define PB   (NPIX/256)       // 196 copy-blocks per sample

// ws float layout:
//   part : [B][S1][RG][S2]  -> 8*17*8*17 = 18496 floats @ 0
//   fpart: [B][RG]          -> 64 floats @ 18496
#define WS_PART  0
#define WS_FPART 18496

// ---------------- kernel 1: corr partials + fused f(l) partials ----------------
// block = (b, i, rg). 256 threads = 4 waves; each wave does 7 rows; lanes 0..55
// each own 4 consecutive x (float4). 6 vector loads per row feed 68 FMAs.
__global__ __launch_bounds__(256) void corr_f_kernel(const float* __restrict__ logits,
                                                     const float* __restrict__ targ,
                                                     float* __restrict__ ws) {
    int bid  = blockIdx.x;              // b*S1*RG + i*RG + rg
    int rg   = bid % RG;
    int i    = (bid / RG) % S1;
    int b    = bid / (RG * S1);
    int tid  = threadIdx.x;
    int lane = tid & 63;
    int w    = tid >> 6;
    bool active = lane < (W_IN / 4);    // 56 active lanes

    float acc[S2];
#pragma unroll
    for (int j = 0; j < S2; ++j) acc[j] = 0.f;
    float fs = 0.f;

    const float* Lb = logits + b * NPIX;
    const float* Tb = targ   + b * TPIX;
    const int y0 = rg * ROWS_PER_BLOCK + w * ROWS_PER_WAVE;
    const bool do_f = (i == 0);

#pragma unroll 2
    for (int r = 0; r < ROWS_PER_WAVE; ++r) {
        int y = y0 + r;
        if (active) {
            const float4 l4 = *(const float4*)(Lb + y * W_IN + lane * 4);
            const float* Tr = Tb + (y + i) * W_T + lane * 4;
            float4 t0 = *(const float4*)(Tr);
            float4 t1 = *(const float4*)(Tr + 4);
            float4 t2 = *(const float4*)(Tr + 8);
            float4 t3 = *(const float4*)(Tr + 12);
            float4 t4 = *(const float4*)(Tr + 16);
            float t[20] = {t0.x,t0.y,t0.z,t0.w, t1.x,t1.y,t1.z,t1.w,
                           t2.x,t2.y,t2.z,t2.w, t3.x,t3.y,t3.z,t3.w,
                           t4.x,t4.y,t4.z,t4.w};
            float l[4] = {l4.x, l4.y, l4.z, l4.w};
#pragma unroll
            for (int j = 0; j < S2; ++j) {
                float s = acc[j];
                s = fmaf(l[0], t[j],     s);
                s = fmaf(l[1], t[j + 1], s);
                s = fmaf(l[2], t[j + 2], s);
                s = fmaf(l[3], t[j + 3], s);
                acc[j] = s;
            }
            if (do_f) {
#pragma unroll
                for (int u = 0; u < 4; ++u) {
                    float v = l[u];
                    fs += fmaxf(v, 0.f) + __logf(1.f + __expf(-fabsf(v)));
                }
            }
        }
    }

#pragma unroll
    for (int j = 0; j < S2; ++j) {
        float v = acc[j];
#pragma unroll
        for (int off = 32; off > 0; off >>= 1)
            v += __shfl_xor(v, off, 64);
        acc[j] = v;
    }

    __shared__ float red[4][S2];
    __shared__ float redf[4];
    if (lane == 0) {
#pragma unroll
        for (int j = 0; j < S2; ++j) red[w][j] = acc[j];
    }
    if (do_f) {
#pragma unroll
        for (int off = 32; off > 0; off >>= 1)
            fs += __shfl_xor(fs, off, 64);
        if (lane == 0) redf[w] = fs;
    }
    __syncthreads();
    if (tid < S2) {
        float v = red[0][tid] + red[1][tid] + red[2][tid] + red[3][tid];
        ws[WS_PART + ((b * S1 + i) * RG + rg) * S2 + tid] = v;
    }
    if (do_f && tid == 0)
        ws[WS_FPART + b * RG + rg] = redf[0] + redf[1] + redf[2] + redf[3];
}

// ---------------- kernel 2: argmax + copy + loss ----------------
__device__ __forceinline__ float part_sum(const float* __restrict__ pp) {
    float v = 0.f;
#pragma unroll
    for (int k = 0; k < RG; ++k) v += pp[k * S2];
    return v;
}

__device__ __forceinline__ void argmax_for(const float* __restrict__ part, int bb,
                                           int tid, int lane, int w,
                                           float* s_v, int* s_i,
                                           float& o_v, int& o_i) {
    float bv = -FLT_MAX;
    int   bs = NS;
    for (int s = tid; s < NS; s += 256) {
        const float* pp = part + ((bb * S1 + s / S2) * RG) * S2 + (s % S2);
        float v = part_sum(pp);
        if (v > bv) { bv = v; bs = s; } // s ascending -> earliest tie kept
    }
#pragma unroll
    for (int off = 32; off > 0; off >>= 1) {
        float ov = __shfl_down(bv, off, 64);
        int   oi = __shfl_down(bs, off, 64);
        if (ov > bv || (ov == bv && oi < bs)) { bv = ov; bs = oi; }
    }
    if (lane == 0) { s_v[w] = bv; s_i[w] = bs; }
    __syncthreads();
    if (tid == 0) {
        float fv = s_v[0]; int fi = s_i[0];
#pragma unroll
        for (int k = 1; k < 4; ++k) {
            if (s_v[k] > fv || (s_v[k] == fv && s_i[k] < fi)) { fv = s_v[k]; fi = s_i[k]; }
        }
        s_v[4] = fv; s_i[4] = fi;
    }
    __syncthreads();
    o_v = s_v[4];
    o_i = s_i[4];
}

__device__ __forceinline__ void argmax_all8(const float* __restrict__ part,
                                            int lane, int w,
                                            float* s_v8, int* s_i8) {
#pragma unroll
    for (int pass = 0; pass < 2; ++pass) {
        int bb = w + pass * 4;
        float bv2 = -FLT_MAX;
        int   bs2 = NS;
        for (int s = lane; s < NS; s += 64) {
            const float* pp = part + ((bb * S1 + s / S2) * RG) * S2 + (s % S2);
            float v = part_sum(pp);
            if (v > bv2) { bv2 = v; bs2 = s; }
        }
#pragma unroll
        for (int off = 32; off > 0; off >>= 1) {
            float ov = __shfl_down(bv2, off, 64);
            int   oi = __shfl_down(bs2, off, 64);
            if (ov > bv2 || (ov == bv2 && oi < bs2)) { bv2 = ov; bs2 = oi; }
        }
        if (lane == 0) { s_v8[bb] = bv2; s_i8[bb] = bs2; }
    }
    __syncthreads();
}

__global__ __launch_bounds__(256) void finish_kernel(const float* __restrict__ targ,
                                                     const float* __restrict__ ws,
                                                     float* __restrict__ out) {
    int blk = blockIdx.x;               // b*PB + p
    int p   = blk % PB;
    int b   = blk / PB;
    int tid = threadIdx.x;
    int lane = tid & 63;
    int w    = tid >> 6;

    const float* part  = ws + WS_PART;
    const float* fpart = ws + WS_FPART;

    __shared__ float s_v[5];
    __shared__ int   s_i[5];
    __shared__ float s_v8[NB];
    __shared__ int   s_i8[NB];

    int best;
    if (blk == 0) {
        argmax_all8(part, lane, w, s_v8, s_i8);
        if (tid == 0) {
            float total = 0.f;
#pragma unroll
            for (int bb = 0; bb < NB; ++bb) {
                float F = 0.f;
#pragma unroll
                for (int k = 0; k < RG; ++k) F += fpart[bb * RG + k];
                total += (F - s_v8[bb]) * (1.0f / (float)NPIX);
            }
            out[0] = total;
        }
        best = s_i8[0];
    } else {
        float bv;
        argmax_for(part, b, tid, lane, w, s_v, s_i, bv, best);
    }

    int pix = p * 256 + tid;            // < 50176 exactly
    int y = pix / W_IN;
    int x = pix - y * W_IN;
    int i = best / S2;
    int j = best - i * S2;
    out[1 + b * NPIX + pix] = targ[b * TPIX + (y + i) * W_T + (x + j)];
}

extern "C" void kernel_launch(void* const* d_in, const int* in_sizes, int n_in,
                              void* d_out, int out_size, void* d_ws, size_t ws_size,
                              hipStream_t stream) {
    const float* logits = (const float*)d_in[0];   // [8,1,224,224]
    const float* targ   = (const float*)d_in[1];   // [8,1,240,240]
    float* out = (float*)d_out;                    // [1 + 8*224*224]
    float* ws  = (float*)d_ws;

    corr_f_kernel<<<NB * S1 * RG, 256, 0, stream>>>(logits, targ, ws);
    finish_kernel<<<NB * PB, 256, 0, stream>>>(targ, ws, out);
}